// Round 1
// baseline (2714.845 us; speedup 1.0000x reference)
//
#include <hip/hip_runtime.h>
#include <math.h>

#define THREADS 256

// Dims: B=8, C(seq)=10, F(dim)=48, H=W=64, HEADS=8, hd=6, MLP=192
// Stage2: NI=80 images, CH=96, PW=384, OUTF=48

// LDS row strides, padded so a 2-row step is != 0 (mod 8) bank-quads
#define TS 52    // tbuf / attn-out rows (48 data floats)
#define QS 152   // qkv rows (144 data floats)
#define HS 196   // h rows (192 data floats)

// ---------------- Kernel A: fused 2-layer transformer, 4 sequences/block ----------------
// LDS: tbuf 8.3KB + sbuf 31.4KB = 39.7KB -> 4 blocks/CU (16 waves)
__global__ __launch_bounds__(THREADS, 4) void ka_transformer(
    const float* __restrict__ x,
    const float* __restrict__ qkv_w, const float* __restrict__ qkv_b,
    const float* __restrict__ proj_w, const float* __restrict__ proj_b,
    const float* __restrict__ ff1_w, const float* __restrict__ ff1_b,
    const float* __restrict__ ff2_w, const float* __restrict__ ff2_b,
    float* __restrict__ t_out)
{
    __shared__ float tbuf[40 * TS];    // token m=s*10+c at row m (stride TS)
    __shared__ float sbuf[40 * HS];    // qkv rows (stride QS) / attn-out rows (stride TS) / h rows (stride HS)
    const int tid = threadIdx.x;
    // XCD swizzle: consecutive logical blocks (sharing 128B lines of x/t_out) on same XCD.
    // 8192 blocks, 8 XCDs, 8192%8==0 -> bijective.
    const int bid = blockIdx.x;
    const int blk = ((bid & 7) << 10) | (bid >> 3);
    const int b   = blk >> 10;           // batch image
    const int hw0 = (blk & 1023) << 2;   // 4 pixels per block

    // stage: tbuf[(s*10+c)*TS + f] = x[(b*480+c*48+f)*4096 + hw0 + s], float4 over s
    for (int cf = tid; cf < 480; cf += THREADS) {
        const int c = cf / 48, f = cf - c * 48;
        const float4 v = *(const float4*)(x + ((size_t)(b * 480 + cf)) * 4096 + hw0);
        float* tb = tbuf + c * TS + f;
        tb[0] = v.x; tb[10 * TS] = v.y; tb[20 * TS] = v.z; tb[30 * TS] = v.w;
    }
    __syncthreads();

    for (int l = 0; l < 2; ++l) {
        const float* qw  = qkv_w + l * 6912;
        const float* qb  = qkv_b + l * 144;
        const float* pw  = proj_w + l * 2304;
        const float* pb  = proj_b + l * 48;
        const float* f1w = ff1_w + l * 9216;
        const float* f1b = ff1_b + l * 192;
        const float* f2w = ff2_w + l * 9216;
        const float* f2b = ff2_b + l * 48;

        // ---- qkv: 40x144, 240 tasks of 2 rows x 12 cols, K=48 ----
        if (tid < 240) {
            const int og = tid % 12, mg = tid / 12;
            const int o0 = og * 12, m0 = mg * 2;
            const float* trow = tbuf + m0 * TS;
            float acc[2][12] = {};
            for (int k = 0; k < 48; k += 4) {
                float4 a0 = *(const float4*)(trow + k);
                float4 a1 = *(const float4*)(trow + TS + k);
                #pragma unroll
                for (int kk = 0; kk < 4; ++kk) {
                    const float* wr = qw + (k + kk) * 144 + o0;
                    float4 w0 = *(const float4*)(wr);
                    float4 w1 = *(const float4*)(wr + 4);
                    float4 w2 = *(const float4*)(wr + 8);
                    const float e0 = (&a0.x)[kk], e1 = (&a1.x)[kk];
                    #pragma unroll
                    for (int c = 0; c < 4; ++c) {
                        const float q0 = (&w0.x)[c], q1 = (&w1.x)[c], q2 = (&w2.x)[c];
                        acc[0][c]     += e0 * q0; acc[1][c]     += e1 * q0;
                        acc[0][4 + c] += e0 * q1; acc[1][4 + c] += e1 * q1;
                        acc[0][8 + c] += e0 * q2; acc[1][8 + c] += e1 * q2;
                    }
                }
            }
            float4 b0 = *(const float4*)(qb + o0);
            float4 b1 = *(const float4*)(qb + o0 + 4);
            float4 b2 = *(const float4*)(qb + o0 + 8);
            #pragma unroll
            for (int r = 0; r < 2; ++r) {
                float* dst = sbuf + (m0 + r) * QS + o0;
                float4 s0, s1, s2;
                s0.x = acc[r][0] + b0.x;  s0.y = acc[r][1] + b0.y;
                s0.z = acc[r][2] + b0.z;  s0.w = acc[r][3] + b0.w;
                s1.x = acc[r][4] + b1.x;  s1.y = acc[r][5] + b1.y;
                s1.z = acc[r][6] + b1.z;  s1.w = acc[r][7] + b1.w;
                s2.x = acc[r][8] + b2.x;  s2.y = acc[r][9] + b2.y;
                s2.z = acc[r][10] + b2.z; s2.w = acc[r][11] + b2.w;
                *(float4*)(dst) = s0; *(float4*)(dst + 4) = s1; *(float4*)(dst + 8) = s2;
            }
        }
        __syncthreads();

        // ---- banded attention: 4 seq x 10 i x 8 h = 320 tasks ----
        float ores[2][6];
        #pragma unroll
        for (int it = 0; it < 2; ++it) {
            int task = tid + it * THREADS;
            if (task < 320) {
                int s = task / 80, r = task % 80, i = r / 8, h = r % 8;
                const float* base = sbuf + s * (10 * QS) + h * 6;
                float kv[6];
                #pragma unroll
                for (int d = 0; d < 6; ++d) kv[d] = base[i * QS + 48 + d];
                int jlo = (i > 0) ? i - 1 : 0;
                int jhi = (i < 9) ? i + 1 : 9;
                float lg[3], mx = -3.4e38f;
                for (int j = jlo; j <= jhi; ++j) {
                    const float* qv = base + j * QS;
                    float sdot = kv[0]*qv[0] + kv[1]*qv[1] + kv[2]*qv[2]
                               + kv[3]*qv[3] + kv[4]*qv[4] + kv[5]*qv[5];
                    sdot *= 0.4082482904638631f;   // 6^-0.5
                    lg[j - jlo] = sdot;
                    mx = fmaxf(mx, sdot);
                }
                int cnt = jhi - jlo + 1;
                float p[3], ps = 0.f;
                for (int jj = 0; jj < cnt; ++jj) { p[jj] = expf(lg[jj] - mx); ps += p[jj]; }
                float inv = 1.0f / ps;
                #pragma unroll
                for (int d = 0; d < 6; ++d) {
                    float ov = 0.f;
                    for (int jj = 0; jj < cnt; ++jj) ov += p[jj] * base[(jlo + jj) * QS + 96 + d];
                    ores[it][d] = ov * inv;
                }
            }
        }
        __syncthreads();
        #pragma unroll
        for (int it = 0; it < 2; ++it) {
            int task = tid + it * THREADS;
            if (task < 320) {
                int s = task / 80, r = task % 80, i = r / 8, h = r % 8;
                float* dst = sbuf + (s * 10 + i) * TS + h * 6;
                #pragma unroll
                for (int d = 0; d < 6; ++d) dst[d] = ores[it][d];
            }
        }
        __syncthreads();

        // ---- proj + residual: 40x48, 240 tasks of 2 rows x 4 cols, K=48 ----
        if (tid < 240) {
            const int og = tid % 12, mg = tid / 12;
            const int o0 = og * 4, m0 = mg * 2;
            const float* orow = sbuf + m0 * TS;
            float acc[2][4] = {};
            for (int k = 0; k < 48; k += 4) {
                float4 a0 = *(const float4*)(orow + k);
                float4 a1 = *(const float4*)(orow + TS + k);
                #pragma unroll
                for (int kk = 0; kk < 4; ++kk) {
                    float4 w = *(const float4*)(pw + (k + kk) * 48 + o0);
                    const float e0 = (&a0.x)[kk], e1 = (&a1.x)[kk];
                    acc[0][0] += e0 * w.x; acc[0][1] += e0 * w.y;
                    acc[0][2] += e0 * w.z; acc[0][3] += e0 * w.w;
                    acc[1][0] += e1 * w.x; acc[1][1] += e1 * w.y;
                    acc[1][2] += e1 * w.z; acc[1][3] += e1 * w.w;
                }
            }
            float4 b4 = *(const float4*)(pb + o0);
            #pragma unroll
            for (int r = 0; r < 2; ++r) {
                float* dst = tbuf + (m0 + r) * TS + o0;
                float4 t4 = *(const float4*)dst;
                t4.x += acc[r][0] + b4.x; t4.y += acc[r][1] + b4.y;
                t4.z += acc[r][2] + b4.z; t4.w += acc[r][3] + b4.w;
                *(float4*)dst = t4;
            }
        }
        __syncthreads();

        // ---- ff1 + gelu: 40x192, 240 tasks of 2 rows x 16 cols, K=48 ----
        if (tid < 240) {
            const int og = tid % 12, mg = tid / 12;
            const int o0 = og * 16, m0 = mg * 2;
            const float* trow = tbuf + m0 * TS;
            float acc[2][16] = {};
            for (int k = 0; k < 48; k += 4) {
                float4 a0 = *(const float4*)(trow + k);
                float4 a1 = *(const float4*)(trow + TS + k);
                #pragma unroll
                for (int kk = 0; kk < 4; ++kk) {
                    const float* wr = f1w + (k + kk) * 192 + o0;
                    const float e0 = (&a0.x)[kk], e1 = (&a1.x)[kk];
                    #pragma unroll
                    for (int g = 0; g < 4; ++g) {
                        float4 w = *(const float4*)(wr + g * 4);
                        acc[0][g*4+0] += e0 * w.x; acc[1][g*4+0] += e1 * w.x;
                        acc[0][g*4+1] += e0 * w.y; acc[1][g*4+1] += e1 * w.y;
                        acc[0][g*4+2] += e0 * w.z; acc[1][g*4+2] += e1 * w.z;
                        acc[0][g*4+3] += e0 * w.w; acc[1][g*4+3] += e1 * w.w;
                    }
                }
            }
            #pragma unroll
            for (int r = 0; r < 2; ++r) {
                float* dst = sbuf + (m0 + r) * HS + o0;
                #pragma unroll
                for (int c = 0; c < 16; ++c) {
                    float v = acc[r][c] + f1b[o0 + c];
                    v = 0.5f * v * (1.f + erff(v * 0.70710678118654752f));
                    dst[c] = v;
                }
            }
        }
        __syncthreads();

        // ---- ff2 + residual: 40x48, 240 tasks of 2 rows x 4 cols, K=192 ----
        if (tid < 240) {
            const int og = tid % 12, mg = tid / 12;
            const int o0 = og * 4, m0 = mg * 2;
            const float* hrow = sbuf + m0 * HS;
            float acc[2][4] = {};
            for (int k = 0; k < 192; k += 4) {
                float4 a0 = *(const float4*)(hrow + k);
                float4 a1 = *(const float4*)(hrow + HS + k);
                #pragma unroll
                for (int kk = 0; kk < 4; ++kk) {
                    float4 w = *(const float4*)(f2w + (k + kk) * 48 + o0);
                    const float e0 = (&a0.x)[kk], e1 = (&a1.x)[kk];
                    acc[0][0] += e0 * w.x; acc[0][1] += e0 * w.y;
                    acc[0][2] += e0 * w.z; acc[0][3] += e0 * w.w;
                    acc[1][0] += e1 * w.x; acc[1][1] += e1 * w.y;
                    acc[1][2] += e1 * w.z; acc[1][3] += e1 * w.w;
                }
            }
            float4 b4 = *(const float4*)(f2b + o0);
            #pragma unroll
            for (int r = 0; r < 2; ++r) {
                float* dst = tbuf + (m0 + r) * TS + o0;
                float4 t4 = *(const float4*)dst;
                t4.x += acc[r][0] + b4.x; t4.y += acc[r][1] + b4.y;
                t4.z += acc[r][2] + b4.z; t4.w += acc[r][3] + b4.w;
                *(float4*)dst = t4;
            }
        }
        __syncthreads();
    }

    // store: t_out pixel-major, 480 contiguous floats per pixel (unpadded)
    {
        float* dst = t_out + ((size_t)(b * 4096 + hw0)) * 480;
        for (int idx = tid; idx < 480; idx += THREADS) {
            int s = idx / 120, rem = idx - s * 120;
            int c = rem / 12, f0 = (rem - c * 12) * 4;
            *(float4*)(dst + s * 480 + c * 48 + f0) =
                *(const float4*)(tbuf + (s * 10 + c) * TS + f0);
        }
    }
}

// ---------------- Kernel B: depthwise 3x3 conv (SAME) + transpose to pixel-major ----------------
__global__ __launch_bounds__(THREADS) void kb_conv(
    const float* __restrict__ x, const float* __restrict__ t_in,
    const float* __restrict__ dw_w, const float* __restrict__ dw_b,
    float* __restrict__ z0)
{
    __shared__ float ct[100 * 97];     // 10x10 halo tile x 96 ch, stride 97 (bank pad)
    const int tid = threadIdx.x;
    const int blk = blockIdx.x;
    const int n = blk >> 6;            // image (b*10+c)
    const int tile = blk & 63;
    const int th0 = (tile >> 3) << 3;
    const int tw0 = (tile & 7) << 3;
    const int b = n / 10, c = n % 10;

    // x half of cat: channels 0..47, planar layout
    for (int idx = tid; idx < 4800; idx += THREADS) {
        int f = idx / 100, p = idx % 100;
        int py = p / 10, px = p % 10;
        int gh = th0 + py - 1, gw = tw0 + px - 1;
        float v = 0.f;
        if ((unsigned)gh < 64u && (unsigned)gw < 64u)
            v = x[((size_t)n * 48 + f) * 4096 + gh * 64 + gw];
        ct[p * 97 + f] = v;
    }
    // y half of cat: channels 48..95, from t (pixel-major)
    for (int idx = tid; idx < 4800; idx += THREADS) {
        int p = idx / 48, f = idx % 48;
        int py = p / 10, px = p % 10;
        int gh = th0 + py - 1, gw = tw0 + px - 1;
        float v = 0.f;
        if ((unsigned)gh < 64u && (unsigned)gw < 64u)
            v = t_in[(size_t)(b * 4096 + gh * 64 + gw) * 480 + c * 48 + f];
        ct[p * 97 + 48 + f] = v;
    }
    __syncthreads();

    #pragma unroll 4
    for (int it = 0; it < 24; ++it) {
        int oidx = tid + it * THREADS;   // 24*256 == 6144 == 64px * 96ch
        int pxl = oidx / 96, ch = oidx % 96;
        int py = pxl >> 3, pxx = pxl & 7;
        const float* wp = dw_w + ch * 9;
        float acc = dw_b[ch];
        #pragma unroll
        for (int dy = 0; dy < 3; ++dy)
            #pragma unroll
            for (int dx = 0; dx < 3; ++dx)
                acc += ct[((py + dy) * 10 + pxx + dx) * 97 + ch] * wp[dy * 3 + dx];
        z0[((size_t)n * 4096 + (th0 + py) * 64 + (tw0 + pxx)) * 96 + ch] = acc;
    }
}

// ---------------- Kernel C: LN + pw1+gelu+pw2 + shortcut, cooperative 64px/block ----------------
// LDS: zb 25.6KB + hb 25.6KB = 51.2KB -> 3 blocks/CU
__global__ __launch_bounds__(THREADS, 3) void kc_mlp(
    const float* __restrict__ x, const float* __restrict__ t_in,
    const float* __restrict__ z0,
    const float* __restrict__ ln_g, const float* __restrict__ ln_b,
    const float* __restrict__ pw1_w, const float* __restrict__ pw1_b,
    const float* __restrict__ pw2_w, const float* __restrict__ pw2_b,
    const float* __restrict__ sc_w, const float* __restrict__ sc_b,
    float* __restrict__ out)
{
    __shared__ float zb[64 * 100];   // z rows (stride 100, 16B aligned); later: cat rows
    __shared__ float hb[64 * 100];   // h chunk rows (stride 100); later: out staging [f*66+px]
    const int tid = threadIdx.x;
    const int blk = blockIdx.x;       // 5120
    const int n   = blk >> 6;         // image 0..79
    const int hw0 = (blk & 63) << 6;  // 64-pixel run
    const size_t pixbase = (size_t)n * 4096 + hw0;

    // ---- stage z0 (contiguous 6144 floats) ----
    for (int idx = tid; idx < 1536; idx += THREADS) {
        float4 v = *(const float4*)(z0 + pixbase * 96 + (size_t)idx * 4);
        int p = idx / 24, c0 = (idx % 24) * 4;
        *(float4*)(&zb[p * 100 + c0]) = v;
    }
    __syncthreads();

    // ---- LayerNorm in place: one lane per pixel ----
    if (tid < 64) {
        float* r = zb + tid * 100;
        float mu = 0.f;
        #pragma unroll
        for (int k = 0; k < 96; ++k) mu += r[k];
        mu *= (1.f / 96.f);
        float var = 0.f;
        #pragma unroll
        for (int k = 0; k < 96; ++k) { float d = r[k] - mu; var += d * d; }
        var *= (1.f / 96.f);
        float rs = rsqrtf(var + 1e-6f);
        #pragma unroll
        for (int k = 0; k < 96; ++k) r[k] = (r[k] - mu) * rs * ln_g[k] + ln_b[k];
    }
    __syncthreads();

    const int pxg = tid >> 4;          // 0..15 (4 pixels each)
    const int sub = tid & 15;          // jg in phase2, fg in phase3
    const int f0  = sub * 3;           // phase3 cols

    float facc[4][3];
    #pragma unroll
    for (int r = 0; r < 4; ++r)
        #pragma unroll
        for (int c = 0; c < 3; ++c) facc[r][c] = pw2_b[f0 + c];

    for (int jc = 0; jc < 4; ++jc) {
        // ---- phase2: h chunk = gelu(z @ pw1[:, jc*96 : jc*96+96] + b), 4px x 6j per thread ----
        {
            const int j0 = jc * 96 + sub * 6;
            const float* zr = zb + pxg * 400;
            float h[4][6] = {};
            for (int k = 0; k < 96; k += 4) {
                float4 a0 = *(const float4*)(zr + k);
                float4 a1 = *(const float4*)(zr + 100 + k);
                float4 a2 = *(const float4*)(zr + 200 + k);
                float4 a3 = *(const float4*)(zr + 300 + k);
                #pragma unroll
                for (int kk = 0; kk < 4; ++kk) {
                    const float* wr = pw1_w + (k + kk) * 384 + j0;
                    const float e0 = (&a0.x)[kk], e1 = (&a1.x)[kk], e2 = (&a2.x)[kk], e3 = (&a3.x)[kk];
                    #pragma unroll
                    for (int c = 0; c < 6; ++c) {
                        const float w = wr[c];
                        h[0][c] += e0 * w; h[1][c] += e1 * w;
                        h[2][c] += e2 * w; h[3][c] += e3 * w;
                    }
                }
            }
            #pragma unroll
            for (int r = 0; r < 4; ++r)
                #pragma unroll
                for (int c = 0; c < 6; ++c) {
                    float v = h[r][c] + pw1_b[j0 + c];
                    v = 0.5f * v * (1.f + erff(v * 0.70710678118654752f));
                    hb[(pxg * 4 + r) * 100 + sub * 6 + c] = v;
                }
        }
        __syncthreads();

        // ---- phase3: facc += h_chunk @ pw2[jc*96 : ..., :], 4px x 3f per thread ----
        {
            const float* hr = hb + pxg * 400;
            for (int k = 0; k < 96; k += 4) {
                float4 a0 = *(const float4*)(hr + k);
                float4 a1 = *(const float4*)(hr + 100 + k);
                float4 a2 = *(const float4*)(hr + 200 + k);
                float4 a3 = *(const float4*)(hr + 300 + k);
                #pragma unroll
                for (int kk = 0; kk < 4; ++kk) {
                    const float* wr = pw2_w + (jc * 96 + k + kk) * 48 + f0;
                    const float w0 = wr[0], w1 = wr[1], w2 = wr[2];
                    const float e0 = (&a0.x)[kk], e1 = (&a1.x)[kk], e2 = (&a2.x)[kk], e3 = (&a3.x)[kk];
                    facc[0][0] += e0 * w0; facc[0][1] += e0 * w1; facc[0][2] += e0 * w2;
                    facc[1][0] += e1 * w0; facc[1][1] += e1 * w1; facc[1][2] += e1 * w2;
                    facc[2][0] += e2 * w0; facc[2][1] += e2 * w1; facc[2][2] += e2 * w2;
                    facc[3][0] += e3 * w0; facc[3][1] += e3 * w1; facc[3][2] += e3 * w2;
                }
            }
        }
        __syncthreads();   // hb reused by next chunk; zb re-read
    }

    // ---- stage cat (x planar ch 0..47, t pixel-major ch 48..95) into zb ----
    for (int idx = tid; idx < 768; idx += THREADS) {
        int ch = idx >> 4, p0 = (idx & 15) << 2;
        float4 v = *(const float4*)(x + ((size_t)n * 48 + ch) * 4096 + hw0 + p0);
        zb[(p0 + 0) * 100 + ch] = v.x; zb[(p0 + 1) * 100 + ch] = v.y;
        zb[(p0 + 2) * 100 + ch] = v.z; zb[(p0 + 3) * 100 + ch] = v.w;
    }
    {
        const size_t tb = ((size_t)(n / 10) * 4096 + hw0);
        const int coff = (n % 10) * 48;
        for (int idx = tid; idx < 768; idx += THREADS) {
            int p = idx / 12, u0 = (idx % 12) * 4;
            float4 v = *(const float4*)(t_in + (tb + p) * 480 + coff + u0);
            *(float4*)(&zb[p * 100 + 48 + u0]) = v;
        }
    }
    __syncthreads();

    // ---- shortcut: facc += cat @ sc_w^T (sc_w is [48 out][96 in]) ----
    {
        const float* cr = zb + pxg * 400;
        for (int k = 0; k < 96; k += 4) {
            float4 a0 = *(const float4*)(cr + k);
            float4 a1 = *(const float4*)(cr + 100 + k);
            float4 a2 = *(const float4*)(cr + 200 + k);
            float4 a3 = *(const float4*)(cr + 300 + k);
            float4 w0 = *(const float4*)(sc_w + (f0 + 0) * 96 + k);
            float4 w1 = *(const float4*)(sc_w + (f0 + 1) * 96 + k);
            float4 w2 = *(const float4*)(sc_w + (f0 + 2) * 96 + k);
            #pragma unroll
            for (int kk = 0; kk < 4; ++kk) {
                const float e0 = (&a0.x)[kk], e1 = (&a1.x)[kk], e2 = (&a2.x)[kk], e3 = (&a3.x)[kk];
                const float q0 = (&w0.x)[kk], q1 = (&w1.x)[kk], q2 = (&w2.x)[kk];
                facc[0][0] += e0 * q0; facc[0][1] += e0 * q1; facc[0][2] += e0 * q2;
                facc[1][0] += e1 * q0; facc[1][1] += e1 * q1; facc[1][2] += e1 * q2;
                facc[2][0] += e2 * q0; facc[2][1] += e2 * q1; facc[2][2] += e2 * q2;
                facc[3][0] += e3 * q0; facc[3][1] += e3 * q1; facc[3][2] += e3 * q2;
            }
        }
    }
    __syncthreads();   // zb/hb done; reuse hb for output staging

    // ---- epilogue: stage [f][px] (stride 66), then coalesced float4 stores ----
    #pragma unroll
    for (int r = 0; r < 4; ++r)
        #pragma unroll
        for (int c = 0; c < 3; ++c)
            hb[(f0 + c) * 66 + pxg * 4 + r] = facc[r][c] + sc_b[f0 + c];
    __syncthreads();
    for (int idx = tid; idx < 768; idx += THREADS) {
        int f = idx / 16, p0 = (idx % 16) * 4;
        float4 v;
        v.x = hb[f * 66 + p0]; v.y = hb[f * 66 + p0 + 1];
        v.z = hb[f * 66 + p0 + 2]; v.w = hb[f * 66 + p0 + 3];
        *(float4*)(out + ((size_t)n * 48 + f) * 4096 + hw0 + p0) = v;
    }
}

extern "C" void kernel_launch(void* const* d_in, const int* in_sizes, int n_in,
                              void* d_out, int out_size, void* d_ws, size_t ws_size,
                              hipStream_t stream) {
    const float* x      = (const float*)d_in[0];
    const float* qkv_w  = (const float*)d_in[1];
    const float* qkv_b  = (const float*)d_in[2];
    const float* proj_w = (const float*)d_in[3];
    const float* proj_b = (const float*)d_in[4];
    const float* ff1_w  = (const float*)d_in[5];
    const float* ff1_b  = (const float*)d_in[6];
    const float* ff2_w  = (const float*)d_in[7];
    const float* ff2_b  = (const float*)d_in[8];
    const float* dw_w   = (const float*)d_in[9];
    const float* dw_b   = (const float*)d_in[10];
    const float* ln_g   = (const float*)d_in[11];
    const float* ln_b   = (const float*)d_in[12];
    const float* pw1_w  = (const float*)d_in[13];
    const float* pw1_b  = (const float*)d_in[14];
    const float* pw2_w  = (const float*)d_in[15];
    const float* pw2_b  = (const float*)d_in[16];
    const float* sc_w   = (const float*)d_in[17];
    const float* sc_b   = (const float*)d_in[18];
    float* out = (float*)d_out;

    // workspace: t_final (B*H*W,10,48) = 15,728,640 f ; z0 (80*4096,96) = 31,457,280 f
    float* t_out = (float*)d_ws;
    float* z0    = t_out + 15728640ull;

    ka_transformer<<<8192, THREADS, 0, stream>>>(x, qkv_w, qkv_b, proj_w, proj_b,
                                                 ff1_w, ff1_b, ff2_w, ff2_b, t_out);
    kb_conv<<<5120, THREADS, 0, stream>>>(x, t_out, dw_w, dw_b, z0);
    kc_mlp<<<5120, THREADS, 0, stream>>>(x, t_out, z0, ln_g, ln_b,
                                         pw1_w, pw1_b, pw2_w, pw2_b, sc_w, sc_b, out);
}

// Round 2
// 2270.270 us; speedup vs baseline: 1.1958x; 1.1958x over previous
//
#include <hip/hip_runtime.h>
#include <math.h>

#define THREADS 256

// Dims: B=8, C(seq)=10, F(dim)=48, H=W=64, HEADS=8, hd=6, MLP=192
// Stage2: NI=80 images, CH=96, PW=384, OUTF=48

// LDS row strides, padded so the r=4 row-group step (4*stride) is == 64 B (mod 128)
// -> mg-groups alias at most 2-way on ds_read_b128 (2-way is free on CDNA4).
#define TS 52    // tbuf / attn-out rows (48 data floats); 4*52*4B = 832B == 64 mod 128
#define QS 152   // qkv rows (144 data floats)
#define HS 196   // h rows (192 data floats);  4*196*4B = 3136B == 64 mod 128

// ---------------- Kernel A: fused 2-layer transformer, 4 sequences/block ----------------
// LDS: tbuf 8.3KB + sbuf 31.4KB = 39.7KB -> 4 blocks/CU (16 waves)
__global__ __launch_bounds__(THREADS, 4) void ka_transformer(
    const float* __restrict__ x,
    const float* __restrict__ qkv_w, const float* __restrict__ qkv_b,
    const float* __restrict__ proj_w, const float* __restrict__ proj_b,
    const float* __restrict__ ff1_w, const float* __restrict__ ff1_b,
    const float* __restrict__ ff2_w, const float* __restrict__ ff2_b,
    float* __restrict__ t_out)
{
    __shared__ float tbuf[40 * TS];    // token m=s*10+c at row m (stride TS)
    __shared__ float sbuf[40 * HS];    // qkv rows (stride QS) / attn-out rows (stride TS) / h rows (stride HS)
    const int tid = threadIdx.x;
    // XCD swizzle: consecutive logical blocks (sharing 128B lines of x/t_out) on same XCD.
    // 8192 blocks, 8 XCDs, 8192%8==0 -> bijective.
    const int bid = blockIdx.x;
    const int blk = ((bid & 7) << 10) | (bid >> 3);
    const int b   = blk >> 10;           // batch image
    const int hw0 = (blk & 1023) << 2;   // 4 pixels per block

    // stage: tbuf[(s*10+c)*TS + f] = x[(b*480+c*48+f)*4096 + hw0 + s], float4 over s
    for (int cf = tid; cf < 480; cf += THREADS) {
        const int c = cf / 48, f = cf - c * 48;
        const float4 v = *(const float4*)(x + ((size_t)(b * 480 + cf)) * 4096 + hw0);
        float* tb = tbuf + c * TS + f;
        tb[0] = v.x; tb[10 * TS] = v.y; tb[20 * TS] = v.z; tb[30 * TS] = v.w;
    }
    __syncthreads();

    for (int l = 0; l < 2; ++l) {
        const float* qw  = qkv_w + l * 6912;
        const float* qb  = qkv_b + l * 144;
        const float* pw  = proj_w + l * 2304;
        const float* pb  = proj_b + l * 48;
        const float* f1w = ff1_w + l * 9216;
        const float* f1b = ff1_b + l * 192;
        const float* f2w = ff2_w + l * 9216;
        const float* f2b = ff2_b + l * 48;

        // ---- qkv: 40x144 = 240 tasks of 4 rows x 6 cols, K=48 ----
        if (tid < 240) {
            const int og = tid % 24, mg = tid / 24;
            const int o0 = og * 6, m0 = mg * 4;
            const float* trow = tbuf + m0 * TS;
            float acc[4][6] = {};
            for (int k = 0; k < 48; k += 4) {
                float4 a0 = *(const float4*)(trow + k);
                float4 a1 = *(const float4*)(trow + TS + k);
                float4 a2 = *(const float4*)(trow + 2 * TS + k);
                float4 a3 = *(const float4*)(trow + 3 * TS + k);
                #pragma unroll
                for (int kk = 0; kk < 4; ++kk) {
                    const float* wr = qw + (k + kk) * 144 + o0;
                    const float e0 = (&a0.x)[kk], e1 = (&a1.x)[kk], e2 = (&a2.x)[kk], e3 = (&a3.x)[kk];
                    #pragma unroll
                    for (int c = 0; c < 6; ++c) {
                        const float w = wr[c];
                        acc[0][c] += e0 * w; acc[1][c] += e1 * w;
                        acc[2][c] += e2 * w; acc[3][c] += e3 * w;
                    }
                }
            }
            #pragma unroll
            for (int r = 0; r < 4; ++r)
                #pragma unroll
                for (int c = 0; c < 6; ++c)
                    sbuf[(m0 + r) * QS + o0 + c] = acc[r][c] + qb[o0 + c];
        }
        __syncthreads();

        // ---- banded attention: 4 seq x 10 i x 8 h = 320 tasks ----
        float ores[2][6];
        #pragma unroll
        for (int it = 0; it < 2; ++it) {
            int task = tid + it * THREADS;
            if (task < 320) {
                int s = task / 80, r = task % 80, i = r / 8, h = r % 8;
                const float* base = sbuf + s * (10 * QS) + h * 6;
                float kv[6];
                #pragma unroll
                for (int d = 0; d < 6; ++d) kv[d] = base[i * QS + 48 + d];
                int jlo = (i > 0) ? i - 1 : 0;
                int jhi = (i < 9) ? i + 1 : 9;
                float lg[3], mx = -3.4e38f;
                for (int j = jlo; j <= jhi; ++j) {
                    const float* qv = base + j * QS;
                    float sdot = kv[0]*qv[0] + kv[1]*qv[1] + kv[2]*qv[2]
                               + kv[3]*qv[3] + kv[4]*qv[4] + kv[5]*qv[5];
                    sdot *= 0.4082482904638631f;   // 6^-0.5
                    lg[j - jlo] = sdot;
                    mx = fmaxf(mx, sdot);
                }
                int cnt = jhi - jlo + 1;
                float p[3], ps = 0.f;
                for (int jj = 0; jj < cnt; ++jj) { p[jj] = expf(lg[jj] - mx); ps += p[jj]; }
                float inv = 1.0f / ps;
                #pragma unroll
                for (int d = 0; d < 6; ++d) {
                    float ov = 0.f;
                    for (int jj = 0; jj < cnt; ++jj) ov += p[jj] * base[(jlo + jj) * QS + 96 + d];
                    ores[it][d] = ov * inv;
                }
            }
        }
        __syncthreads();
        #pragma unroll
        for (int it = 0; it < 2; ++it) {
            int task = tid + it * THREADS;
            if (task < 320) {
                int s = task / 80, r = task % 80, i = r / 8, h = r % 8;
                float* dst = sbuf + (s * 10 + i) * TS + h * 6;
                #pragma unroll
                for (int d = 0; d < 6; ++d) dst[d] = ores[it][d];
            }
        }
        __syncthreads();

        // ---- proj + residual: 40x48 = 240 tasks of 4 rows x 2 cols, K=48 ----
        if (tid < 240) {
            const int og = tid % 24, mg = tid / 24;
            const int o0 = og * 2, m0 = mg * 4;
            const float* orow = sbuf + m0 * TS;
            float acc[4][2] = {};
            for (int k = 0; k < 48; k += 4) {
                float4 a0 = *(const float4*)(orow + k);
                float4 a1 = *(const float4*)(orow + TS + k);
                float4 a2 = *(const float4*)(orow + 2 * TS + k);
                float4 a3 = *(const float4*)(orow + 3 * TS + k);
                #pragma unroll
                for (int kk = 0; kk < 4; ++kk) {
                    const float* wr = pw + (k + kk) * 48 + o0;
                    const float w0 = wr[0], w1 = wr[1];
                    const float e0 = (&a0.x)[kk], e1 = (&a1.x)[kk], e2 = (&a2.x)[kk], e3 = (&a3.x)[kk];
                    acc[0][0] += e0 * w0; acc[0][1] += e0 * w1;
                    acc[1][0] += e1 * w0; acc[1][1] += e1 * w1;
                    acc[2][0] += e2 * w0; acc[2][1] += e2 * w1;
                    acc[3][0] += e3 * w0; acc[3][1] += e3 * w1;
                }
            }
            #pragma unroll
            for (int r = 0; r < 4; ++r)
                #pragma unroll
                for (int c = 0; c < 2; ++c)
                    tbuf[(m0 + r) * TS + o0 + c] += acc[r][c] + pb[o0 + c];
        }
        __syncthreads();

        // ---- ff1 + gelu: 40x192 = 240 tasks of 4 rows x 8 cols, K=48 ----
        if (tid < 240) {
            const int og = tid % 24, mg = tid / 24;
            const int o0 = og * 8, m0 = mg * 4;
            const float* trow = tbuf + m0 * TS;
            float acc[4][8] = {};
            for (int k = 0; k < 48; k += 4) {
                float4 a0 = *(const float4*)(trow + k);
                float4 a1 = *(const float4*)(trow + TS + k);
                float4 a2 = *(const float4*)(trow + 2 * TS + k);
                float4 a3 = *(const float4*)(trow + 3 * TS + k);
                #pragma unroll
                for (int kk = 0; kk < 4; ++kk) {
                    const float* wr = f1w + (k + kk) * 192 + o0;
                    const float e0 = (&a0.x)[kk], e1 = (&a1.x)[kk], e2 = (&a2.x)[kk], e3 = (&a3.x)[kk];
                    #pragma unroll
                    for (int c = 0; c < 8; ++c) {
                        const float w = wr[c];
                        acc[0][c] += e0 * w; acc[1][c] += e1 * w;
                        acc[2][c] += e2 * w; acc[3][c] += e3 * w;
                    }
                }
            }
            #pragma unroll
            for (int r = 0; r < 4; ++r)
                #pragma unroll
                for (int c = 0; c < 8; ++c) {
                    float v = acc[r][c] + f1b[o0 + c];
                    v = 0.5f * v * (1.f + erff(v * 0.70710678118654752f));
                    sbuf[(m0 + r) * HS + o0 + c] = v;
                }
        }
        __syncthreads();

        // ---- ff2 + residual: 40x48 = 240 tasks of 4 rows x 2 cols, K=192 ----
        if (tid < 240) {
            const int og = tid % 24, mg = tid / 24;
            const int o0 = og * 2, m0 = mg * 4;
            const float* hrow = sbuf + m0 * HS;
            float acc[4][2] = {};
            for (int k = 0; k < 192; k += 4) {
                float4 a0 = *(const float4*)(hrow + k);
                float4 a1 = *(const float4*)(hrow + HS + k);
                float4 a2 = *(const float4*)(hrow + 2 * HS + k);
                float4 a3 = *(const float4*)(hrow + 3 * HS + k);
                #pragma unroll
                for (int kk = 0; kk < 4; ++kk) {
                    const float* wr = f2w + (k + kk) * 48 + o0;
                    const float w0 = wr[0], w1 = wr[1];
                    const float e0 = (&a0.x)[kk], e1 = (&a1.x)[kk], e2 = (&a2.x)[kk], e3 = (&a3.x)[kk];
                    acc[0][0] += e0 * w0; acc[0][1] += e0 * w1;
                    acc[1][0] += e1 * w0; acc[1][1] += e1 * w1;
                    acc[2][0] += e2 * w0; acc[2][1] += e2 * w1;
                    acc[3][0] += e3 * w0; acc[3][1] += e3 * w1;
                }
            }
            #pragma unroll
            for (int r = 0; r < 4; ++r)
                #pragma unroll
                for (int c = 0; c < 2; ++c)
                    tbuf[(m0 + r) * TS + o0 + c] += acc[r][c] + f2b[o0 + c];
        }
        __syncthreads();
    }

    // store: t_out pixel-major, 480 contiguous floats per pixel (unpadded)
    {
        float* dst = t_out + ((size_t)(b * 4096 + hw0)) * 480;
        for (int idx = tid; idx < 480; idx += THREADS) {
            int s = idx / 120, rem = idx - s * 120;
            int c = rem / 12, f0 = (rem - c * 12) * 4;
            *(float4*)(dst + s * 480 + c * 48 + f0) =
                *(const float4*)(tbuf + (s * 10 + c) * TS + f0);
        }
    }
}

// ---------------- Kernel B: depthwise 3x3 conv (SAME) + transpose to pixel-major ----------------
__global__ __launch_bounds__(THREADS) void kb_conv(
    const float* __restrict__ x, const float* __restrict__ t_in,
    const float* __restrict__ dw_w, const float* __restrict__ dw_b,
    float* __restrict__ z0)
{
    __shared__ float ct[100 * 97];     // 10x10 halo tile x 96 ch, stride 97 (bank pad)
    const int tid = threadIdx.x;
    const int blk = blockIdx.x;
    const int n = blk >> 6;            // image (b*10+c)
    const int tile = blk & 63;
    const int th0 = (tile >> 3) << 3;
    const int tw0 = (tile & 7) << 3;
    const int b = n / 10, c = n % 10;

    // x half of cat: channels 0..47, planar layout
    for (int idx = tid; idx < 4800; idx += THREADS) {
        int f = idx / 100, p = idx % 100;
        int py = p / 10, px = p % 10;
        int gh = th0 + py - 1, gw = tw0 + px - 1;
        float v = 0.f;
        if ((unsigned)gh < 64u && (unsigned)gw < 64u)
            v = x[((size_t)n * 48 + f) * 4096 + gh * 64 + gw];
        ct[p * 97 + f] = v;
    }
    // y half of cat: channels 48..95, from t (pixel-major)
    for (int idx = tid; idx < 4800; idx += THREADS) {
        int p = idx / 48, f = idx % 48;
        int py = p / 10, px = p % 10;
        int gh = th0 + py - 1, gw = tw0 + px - 1;
        float v = 0.f;
        if ((unsigned)gh < 64u && (unsigned)gw < 64u)
            v = t_in[(size_t)(b * 4096 + gh * 64 + gw) * 480 + c * 48 + f];
        ct[p * 97 + 48 + f] = v;
    }
    __syncthreads();

    #pragma unroll 4
    for (int it = 0; it < 24; ++it) {
        int oidx = tid + it * THREADS;   // 24*256 == 6144 == 64px * 96ch
        int pxl = oidx / 96, ch = oidx % 96;
        int py = pxl >> 3, pxx = pxl & 7;
        const float* wp = dw_w + ch * 9;
        float acc = dw_b[ch];
        #pragma unroll
        for (int dy = 0; dy < 3; ++dy)
            #pragma unroll
            for (int dx = 0; dx < 3; ++dx)
                acc += ct[((py + dy) * 10 + pxx + dx) * 97 + ch] * wp[dy * 3 + dx];
        z0[((size_t)n * 4096 + (th0 + py) * 64 + (tw0 + pxx)) * 96 + ch] = acc;
    }
}

// ---------------- Kernel C: LN + pw1+gelu+pw2 + shortcut, cooperative 64px/block ----------------
// LDS: zb 25.6KB + hb 25.6KB = 51.2KB -> 3 blocks/CU
__global__ __launch_bounds__(THREADS, 3) void kc_mlp(
    const float* __restrict__ x, const float* __restrict__ t_in,
    const float* __restrict__ z0,
    const float* __restrict__ ln_g, const float* __restrict__ ln_b,
    const float* __restrict__ pw1_w, const float* __restrict__ pw1_b,
    const float* __restrict__ pw2_w, const float* __restrict__ pw2_b,
    const float* __restrict__ sc_w, const float* __restrict__ sc_b,
    float* __restrict__ out)
{
    __shared__ float zb[64 * 100];   // z rows (stride 100, 16B aligned); later: cat rows
    __shared__ float hb[64 * 100];   // h chunk rows (stride 100); later: out staging [f*66+px]
    const int tid = threadIdx.x;
    const int blk = blockIdx.x;       // 5120
    const int n   = blk >> 6;         // image 0..79
    const int hw0 = (blk & 63) << 6;  // 64-pixel run
    const size_t pixbase = (size_t)n * 4096 + hw0;

    // ---- stage z0 (contiguous 6144 floats) ----
    for (int idx = tid; idx < 1536; idx += THREADS) {
        float4 v = *(const float4*)(z0 + pixbase * 96 + (size_t)idx * 4);
        int p = idx / 24, c0 = (idx % 24) * 4;
        *(float4*)(&zb[p * 100 + c0]) = v;
    }
    __syncthreads();

    // ---- LayerNorm in place: one lane per pixel ----
    if (tid < 64) {
        float* r = zb + tid * 100;
        float mu = 0.f;
        #pragma unroll
        for (int k = 0; k < 96; ++k) mu += r[k];
        mu *= (1.f / 96.f);
        float var = 0.f;
        #pragma unroll
        for (int k = 0; k < 96; ++k) { float d = r[k] - mu; var += d * d; }
        var *= (1.f / 96.f);
        float rs = rsqrtf(var + 1e-6f);
        #pragma unroll
        for (int k = 0; k < 96; ++k) r[k] = (r[k] - mu) * rs * ln_g[k] + ln_b[k];
    }
    __syncthreads();

    const int pxg = tid >> 4;          // 0..15 (4 pixels each)
    const int sub = tid & 15;          // jg in phase2, fg in phase3
    const int f0  = sub * 3;           // phase3 cols

    float facc[4][3];
    #pragma unroll
    for (int r = 0; r < 4; ++r)
        #pragma unroll
        for (int c = 0; c < 3; ++c) facc[r][c] = pw2_b[f0 + c];

    for (int jc = 0; jc < 4; ++jc) {
        // ---- phase2: h chunk = gelu(z @ pw1[:, jc*96 : jc*96+96] + b), 4px x 6j per thread ----
        {
            const int j0 = jc * 96 + sub * 6;
            const float* zr = zb + pxg * 400;
            float h[4][6] = {};
            for (int k = 0; k < 96; k += 4) {
                float4 a0 = *(const float4*)(zr + k);
                float4 a1 = *(const float4*)(zr + 100 + k);
                float4 a2 = *(const float4*)(zr + 200 + k);
                float4 a3 = *(const float4*)(zr + 300 + k);
                #pragma unroll
                for (int kk = 0; kk < 4; ++kk) {
                    const float* wr = pw1_w + (k + kk) * 384 + j0;
                    const float e0 = (&a0.x)[kk], e1 = (&a1.x)[kk], e2 = (&a2.x)[kk], e3 = (&a3.x)[kk];
                    #pragma unroll
                    for (int c = 0; c < 6; ++c) {
                        const float w = wr[c];
                        h[0][c] += e0 * w; h[1][c] += e1 * w;
                        h[2][c] += e2 * w; h[3][c] += e3 * w;
                    }
                }
            }
            #pragma unroll
            for (int r = 0; r < 4; ++r)
                #pragma unroll
                for (int c = 0; c < 6; ++c) {
                    float v = h[r][c] + pw1_b[j0 + c];
                    v = 0.5f * v * (1.f + erff(v * 0.70710678118654752f));
                    hb[(pxg * 4 + r) * 100 + sub * 6 + c] = v;
                }
        }
        __syncthreads();

        // ---- phase3: facc += h_chunk @ pw2[jc*96 : ..., :], 4px x 3f per thread ----
        {
            const float* hr = hb + pxg * 400;
            for (int k = 0; k < 96; k += 4) {
                float4 a0 = *(const float4*)(hr + k);
                float4 a1 = *(const float4*)(hr + 100 + k);
                float4 a2 = *(const float4*)(hr + 200 + k);
                float4 a3 = *(const float4*)(hr + 300 + k);
                #pragma unroll
                for (int kk = 0; kk < 4; ++kk) {
                    const float* wr = pw2_w + (jc * 96 + k + kk) * 48 + f0;
                    const float w0 = wr[0], w1 = wr[1], w2 = wr[2];
                    const float e0 = (&a0.x)[kk], e1 = (&a1.x)[kk], e2 = (&a2.x)[kk], e3 = (&a3.x)[kk];
                    facc[0][0] += e0 * w0; facc[0][1] += e0 * w1; facc[0][2] += e0 * w2;
                    facc[1][0] += e1 * w0; facc[1][1] += e1 * w1; facc[1][2] += e1 * w2;
                    facc[2][0] += e2 * w0; facc[2][1] += e2 * w1; facc[2][2] += e2 * w2;
                    facc[3][0] += e3 * w0; facc[3][1] += e3 * w1; facc[3][2] += e3 * w2;
                }
            }
        }
        __syncthreads();   // hb reused by next chunk; zb re-read
    }

    // ---- stage cat (x planar ch 0..47, t pixel-major ch 48..95) into zb ----
    for (int idx = tid; idx < 768; idx += THREADS) {
        int ch = idx >> 4, p0 = (idx & 15) << 2;
        float4 v = *(const float4*)(x + ((size_t)n * 48 + ch) * 4096 + hw0 + p0);
        zb[(p0 + 0) * 100 + ch] = v.x; zb[(p0 + 1) * 100 + ch] = v.y;
        zb[(p0 + 2) * 100 + ch] = v.z; zb[(p0 + 3) * 100 + ch] = v.w;
    }
    {
        const size_t tb = ((size_t)(n / 10) * 4096 + hw0);
        const int coff = (n % 10) * 48;
        for (int idx = tid; idx < 768; idx += THREADS) {
            int p = idx / 12, u0 = (idx % 12) * 4;
            float4 v = *(const float4*)(t_in + (tb + p) * 480 + coff + u0);
            *(float4*)(&zb[p * 100 + 48 + u0]) = v;
        }
    }
    __syncthreads();

    // ---- shortcut: facc += cat @ sc_w^T (sc_w is [48 out][96 in]) ----
    {
        const float* cr = zb + pxg * 400;
        for (int k = 0; k < 96; k += 4) {
            float4 a0 = *(const float4*)(cr + k);
            float4 a1 = *(const float4*)(cr + 100 + k);
            float4 a2 = *(const float4*)(cr + 200 + k);
            float4 a3 = *(const float4*)(cr + 300 + k);
            float4 w0 = *(const float4*)(sc_w + (f0 + 0) * 96 + k);
            float4 w1 = *(const float4*)(sc_w + (f0 + 1) * 96 + k);
            float4 w2 = *(const float4*)(sc_w + (f0 + 2) * 96 + k);
            #pragma unroll
            for (int kk = 0; kk < 4; ++kk) {
                const float e0 = (&a0.x)[kk], e1 = (&a1.x)[kk], e2 = (&a2.x)[kk], e3 = (&a3.x)[kk];
                const float q0 = (&w0.x)[kk], q1 = (&w1.x)[kk], q2 = (&w2.x)[kk];
                facc[0][0] += e0 * q0; facc[0][1] += e0 * q1; facc[0][2] += e0 * q2;
                facc[1][0] += e1 * q0; facc[1][1] += e1 * q1; facc[1][2] += e1 * q2;
                facc[2][0] += e2 * q0; facc[2][1] += e2 * q1; facc[2][2] += e2 * q2;
                facc[3][0] += e3 * q0; facc[3][1] += e3 * q1; facc[3][2] += e3 * q2;
            }
        }
    }
    __syncthreads();   // zb/hb done; reuse hb for output staging

    // ---- epilogue: stage [f][px] (stride 66), then coalesced float4 stores ----
    #pragma unroll
    for (int r = 0; r < 4; ++r)
        #pragma unroll
        for (int c = 0; c < 3; ++c)
            hb[(f0 + c) * 66 + pxg * 4 + r] = facc[r][c] + sc_b[f0 + c];
    __syncthreads();
    for (int idx = tid; idx < 768; idx += THREADS) {
        int f = idx / 16, p0 = (idx % 16) * 4;
        float4 v;
        v.x = hb[f * 66 + p0]; v.y = hb[f * 66 + p0 + 1];
        v.z = hb[f * 66 + p0 + 2]; v.w = hb[f * 66 + p0 + 3];
        *(float4*)(out + ((size_t)n * 48 + f) * 4096 + hw0 + p0) = v;
    }
}

extern "C" void kernel_launch(void* const* d_in, const int* in_sizes, int n_in,
                              void* d_out, int out_size, void* d_ws, size_t ws_size,
                              hipStream_t stream) {
    const float* x      = (const float*)d_in[0];
    const float* qkv_w  = (const float*)d_in[1];
    const float* qkv_b  = (const float*)d_in[2];
    const float* proj_w = (const float*)d_in[3];
    const float* proj_b = (const float*)d_in[4];
    const float* ff1_w  = (const float*)d_in[5];
    const float* ff1_b  = (const float*)d_in[6];
    const float* ff2_w  = (const float*)d_in[7];
    const float* ff2_b  = (const float*)d_in[8];
    const float* dw_w   = (const float*)d_in[9];
    const float* dw_b   = (const float*)d_in[10];
    const float* ln_g   = (const float*)d_in[11];
    const float* ln_b   = (const float*)d_in[12];
    const float* pw1_w  = (const float*)d_in[13];
    const float* pw1_b  = (const float*)d_in[14];
    const float* pw2_w  = (const float*)d_in[15];
    const float* pw2_b  = (const float*)d_in[16];
    const float* sc_w   = (const float*)d_in[17];
    const float* sc_b   = (const float*)d_in[18];
    float* out = (float*)d_out;

    // workspace: t_final (B*H*W,10,48) = 15,728,640 f ; z0 (80*4096,96) = 31,457,280 f
    float* t_out = (float*)d_ws;
    float* z0    = t_out + 15728640ull;

    ka_transformer<<<8192, THREADS, 0, stream>>>(x, qkv_w, qkv_b, proj_w, proj_b,
                                                 ff1_w, ff1_b, ff2_w, ff2_b, t_out);
    kb_conv<<<5120, THREADS, 0, stream>>>(x, t_out, dw_w, dw_b, z0);
    kc_mlp<<<5120, THREADS, 0, stream>>>(x, t_out, z0, ln_g, ln_b,
                                         pw1_w, pw1_b, pw2_w, pw2_b, sc_w, sc_b, out);
}

// Round 3
// 1981.157 us; speedup vs baseline: 1.3703x; 1.1459x over previous
//
#include <hip/hip_runtime.h>
#include <math.h>

#define THREADS 256

// Dims: B=8, C(seq)=10, F(dim)=48, H=W=64, HEADS=8, hd=6, MLP=192
// Stage2: NI=80 images, CH=96, PW=384, OUTF=48

// ---------------- Kernel A (rewrite): lane = token ----------------
// One wave per block; 6 sequences (pixels) per wave: lane = s*10 + c, s<6, c<10.
// t row per lane lives in LDS (stride 49 floats -> (17L+k)%32 banks, 2 lanes/bank = free).
// Weights are wave-uniform -> s_load (SMEM pipe). Attention in registers via shfl +-1.
// No __syncthreads anywhere (all LDS lane-private).
#define LKS 49

__global__ __launch_bounds__(64, 3) void ka2_transformer(
    const float* __restrict__ x,
    const float* __restrict__ qkv_w, const float* __restrict__ qkv_b,
    const float* __restrict__ proj_w, const float* __restrict__ proj_b,
    const float* __restrict__ ff1_w, const float* __restrict__ ff1_b,
    const float* __restrict__ ff2_w, const float* __restrict__ ff2_b,
    float* __restrict__ t_out)
{
    __shared__ float tl[64 * LKS];     // per-lane token row (48 data + 1 pad)
    const int lane = threadIdx.x;

    // bijective XCD swizzle (grid not divisible by 8): chunked assignment
    const int nb  = gridDim.x;
    const int q8  = nb >> 3, r8 = nb & 7;
    const int xcd = blockIdx.x & 7, idx = blockIdx.x >> 3;
    const int wg  = (xcd < r8) ? xcd * (q8 + 1) + idx
                               : r8 * (q8 + 1) + (xcd - r8) * q8 + idx;

    const int s = lane / 10;
    const int c = lane - s * 10;                 // seq position 0..9
    const int g = wg * 6 + s;                    // global pixel (sequence) id
    const bool act = (lane < 60) && (g < 32768);
    const int b   = g >> 12;                     // batch image
    const int pix = g & 4095;

    float* tr = tl + lane * LKS;

    // ---- prologue: gather this token's 48 features (strided dwords, one-time) ----
    if (act) {
        const float* xp = x + ((size_t)(b * 480 + c * 48)) * 4096 + pix;
        #pragma unroll
        for (int f = 0; f < 48; ++f) tr[f] = xp[(size_t)f * 4096];
    } else {
        #pragma unroll
        for (int f = 0; f < 48; ++f) tr[f] = 0.f;
    }

    const float scale = 0.4082482904638631f;     // 6^-0.5
    const float NEG = -3.4e38f;

    for (int l = 0; l < 2; ++l) {
        const float* qw  = qkv_w + l * 6912;
        const float* qb  = qkv_b + l * 144;
        const float* pw  = proj_w + l * 2304;
        const float* pb  = proj_b + l * 48;
        const float* f1w = ff1_w + l * 9216;
        const float* f1b = ff1_b + l * 192;
        const float* f2w = ff2_w + l * 9216;
        const float* f2b = ff2_b + l * 48;

        // ---- attention block: per head, qkv -> in-register attention -> proj accum ----
        float pacc[48];
        #pragma unroll
        for (int o = 0; o < 48; ++o) pacc[o] = 0.f;

        for (int h = 0; h < 8; ++h) {
            float qa[6], ka[6], va[6];
            #pragma unroll
            for (int d = 0; d < 6; ++d) { qa[d] = 0.f; ka[d] = 0.f; va[d] = 0.f; }

            // qkv GEMV: contract over own t row (LDS), weights via s_load
            for (int k = 0; k < 48; ++k) {
                const float tk = tr[k];
                const float* wr = qw + k * 144 + h * 6;
                #pragma unroll
                for (int d = 0; d < 6; ++d) {
                    qa[d] += tk * wr[d];
                    ka[d] += tk * wr[48 + d];
                    va[d] += tk * wr[96 + d];
                }
            }
            #pragma unroll
            for (int d = 0; d < 6; ++d) {
                qa[d] += qb[h * 6 + d];
                ka[d] += qb[48 + h * 6 + d];
                va[d] += qb[96 + h * 6 + d];
            }

            // neighbors via shfl (lane +-1 == seq position +-1; band mask handles edges)
            float qm[6], qp[6], vm[6], vp[6];
            #pragma unroll
            for (int d = 0; d < 6; ++d) {
                qm[d] = __shfl_up(qa[d], 1);
                qp[d] = __shfl_down(qa[d], 1);
                vm[d] = __shfl_up(va[d], 1);
                vp[d] = __shfl_down(va[d], 1);
            }
            float s0 = 0.f, sm = 0.f, sp = 0.f;
            #pragma unroll
            for (int d = 0; d < 6; ++d) {
                s0 += ka[d] * qa[d];
                sm += ka[d] * qm[d];
                sp += ka[d] * qp[d];
            }
            s0 *= scale; sm *= scale; sp *= scale;
            if (c == 0) sm = NEG;
            if (c == 9) sp = NEG;
            const float mx = fmaxf(s0, fmaxf(sm, sp));
            const float em = expf(sm - mx), e0 = expf(s0 - mx), ep = expf(sp - mx);
            const float inv = 1.0f / (em + e0 + ep);

            // o[d] then proj accumulation (contraction index h*6+d sequential 0..47)
            #pragma unroll
            for (int d = 0; d < 6; ++d) {
                const float ov = (em * vm[d] + e0 * va[d] + ep * vp[d]) * inv;
                const float* wr = pw + (h * 6 + d) * 48;
                #pragma unroll
                for (int o = 0; o < 48; ++o) pacc[o] += ov * wr[o];
            }
        }
        // residual: t += proj + bias
        #pragma unroll
        for (int f = 0; f < 48; ++f) tr[f] += pacc[f] + pb[f];

        // ---- MLP: ff1(+gelu) and ff2 fused per 24-wide chunk ----
        float facc[48];
        #pragma unroll
        for (int o = 0; o < 48; ++o) facc[o] = 0.f;

        for (int cc = 0; cc < 8; ++cc) {
            float ha[24];
            #pragma unroll
            for (int j = 0; j < 24; ++j) ha[j] = 0.f;

            for (int k = 0; k < 48; ++k) {
                const float tk = tr[k];
                const float* wr = f1w + k * 192 + cc * 24;
                #pragma unroll
                for (int j = 0; j < 24; ++j) ha[j] += tk * wr[j];
            }
            #pragma unroll
            for (int j = 0; j < 24; ++j) {
                float v = ha[j] + f1b[cc * 24 + j];
                ha[j] = 0.5f * v * (1.f + erff(v * 0.70710678118654752f));
            }
            // ff2: contract over j (registers, fully unrolled), accumulate facc
            #pragma unroll
            for (int j = 0; j < 24; ++j) {
                const float hj = ha[j];
                const float* wr = f2w + (cc * 24 + j) * 48;
                #pragma unroll
                for (int o = 0; o < 48; ++o) facc[o] += hj * wr[o];
            }
        }
        // residual: t += ff2 + bias
        #pragma unroll
        for (int f = 0; f < 48; ++f) tr[f] += facc[f] + f2b[f];
    }

    // ---- store: t_out[pixel*480 + c*48 + f], 12 float4 per lane ----
    if (act) {
        float* dst = t_out + (size_t)g * 480 + c * 48;
        #pragma unroll
        for (int u = 0; u < 12; ++u) {
            float4 v;
            v.x = tr[u * 4]; v.y = tr[u * 4 + 1];
            v.z = tr[u * 4 + 2]; v.w = tr[u * 4 + 3];
            *(float4*)(dst + u * 4) = v;
        }
    }
}

// ---------------- Kernel B: depthwise 3x3 conv (SAME) + transpose to pixel-major ----------------
__global__ __launch_bounds__(THREADS) void kb_conv(
    const float* __restrict__ x, const float* __restrict__ t_in,
    const float* __restrict__ dw_w, const float* __restrict__ dw_b,
    float* __restrict__ z0)
{
    __shared__ float ct[100 * 97];     // 10x10 halo tile x 96 ch, stride 97 (bank pad)
    const int tid = threadIdx.x;
    const int blk = blockIdx.x;
    const int n = blk >> 6;            // image (b*10+c)
    const int tile = blk & 63;
    const int th0 = (tile >> 3) << 3;
    const int tw0 = (tile & 7) << 3;
    const int b = n / 10, c = n % 10;

    // x half of cat: channels 0..47, planar layout
    for (int idx = tid; idx < 4800; idx += THREADS) {
        int f = idx / 100, p = idx % 100;
        int py = p / 10, px = p % 10;
        int gh = th0 + py - 1, gw = tw0 + px - 1;
        float v = 0.f;
        if ((unsigned)gh < 64u && (unsigned)gw < 64u)
            v = x[((size_t)n * 48 + f) * 4096 + gh * 64 + gw];
        ct[p * 97 + f] = v;
    }
    // y half of cat: channels 48..95, from t (pixel-major)
    for (int idx = tid; idx < 4800; idx += THREADS) {
        int p = idx / 48, f = idx % 48;
        int py = p / 10, px = p % 10;
        int gh = th0 + py - 1, gw = tw0 + px - 1;
        float v = 0.f;
        if ((unsigned)gh < 64u && (unsigned)gw < 64u)
            v = t_in[(size_t)(b * 4096 + gh * 64 + gw) * 480 + c * 48 + f];
        ct[p * 97 + 48 + f] = v;
    }
    __syncthreads();

    #pragma unroll 4
    for (int it = 0; it < 24; ++it) {
        int oidx = tid + it * THREADS;   // 24*256 == 6144 == 64px * 96ch
        int pxl = oidx / 96, ch = oidx % 96;
        int py = pxl >> 3, pxx = pxl & 7;
        const float* wp = dw_w + ch * 9;
        float acc = dw_b[ch];
        #pragma unroll
        for (int dy = 0; dy < 3; ++dy)
            #pragma unroll
            for (int dx = 0; dx < 3; ++dx)
                acc += ct[((py + dy) * 10 + pxx + dx) * 97 + ch] * wp[dy * 3 + dx];
        z0[((size_t)n * 4096 + (th0 + py) * 64 + (tw0 + pxx)) * 96 + ch] = acc;
    }
}

// ---------------- Kernel C: LN + pw1+gelu+pw2 + shortcut, cooperative 64px/block ----------------
// LDS: zb 25.6KB + hb 25.6KB = 51.2KB -> 3 blocks/CU
__global__ __launch_bounds__(THREADS, 3) void kc_mlp(
    const float* __restrict__ x, const float* __restrict__ t_in,
    const float* __restrict__ z0,
    const float* __restrict__ ln_g, const float* __restrict__ ln_b,
    const float* __restrict__ pw1_w, const float* __restrict__ pw1_b,
    const float* __restrict__ pw2_w, const float* __restrict__ pw2_b,
    const float* __restrict__ sc_w, const float* __restrict__ sc_b,
    float* __restrict__ out)
{
    __shared__ float zb[64 * 100];   // z rows (stride 100, 16B aligned); later: cat rows
    __shared__ float hb[64 * 100];   // h chunk rows (stride 100); later: out staging [f*66+px]
    const int tid = threadIdx.x;
    const int blk = blockIdx.x;       // 5120
    const int n   = blk >> 6;         // image 0..79
    const int hw0 = (blk & 63) << 6;  // 64-pixel run
    const size_t pixbase = (size_t)n * 4096 + hw0;

    // ---- stage z0 (contiguous 6144 floats) ----
    for (int idx = tid; idx < 1536; idx += THREADS) {
        float4 v = *(const float4*)(z0 + pixbase * 96 + (size_t)idx * 4);
        int p = idx / 24, c0 = (idx % 24) * 4;
        *(float4*)(&zb[p * 100 + c0]) = v;
    }
    __syncthreads();

    // ---- LayerNorm in place: one lane per pixel ----
    if (tid < 64) {
        float* r = zb + tid * 100;
        float mu = 0.f;
        #pragma unroll
        for (int k = 0; k < 96; ++k) mu += r[k];
        mu *= (1.f / 96.f);
        float var = 0.f;
        #pragma unroll
        for (int k = 0; k < 96; ++k) { float d = r[k] - mu; var += d * d; }
        var *= (1.f / 96.f);
        float rs = rsqrtf(var + 1e-6f);
        #pragma unroll
        for (int k = 0; k < 96; ++k) r[k] = (r[k] - mu) * rs * ln_g[k] + ln_b[k];
    }
    __syncthreads();

    const int pxg = tid >> 4;          // 0..15 (4 pixels each)
    const int sub = tid & 15;          // jg in phase2, fg in phase3
    const int f0  = sub * 3;           // phase3 cols

    float facc[4][3];
    #pragma unroll
    for (int r = 0; r < 4; ++r)
        #pragma unroll
        for (int c = 0; c < 3; ++c) facc[r][c] = pw2_b[f0 + c];

    for (int jc = 0; jc < 4; ++jc) {
        // ---- phase2: h chunk = gelu(z @ pw1[:, jc*96 : jc*96+96] + b), 4px x 6j per thread ----
        {
            const int j0 = jc * 96 + sub * 6;
            const float* zr = zb + pxg * 400;
            float h[4][6] = {};
            for (int k = 0; k < 96; k += 4) {
                float4 a0 = *(const float4*)(zr + k);
                float4 a1 = *(const float4*)(zr + 100 + k);
                float4 a2 = *(const float4*)(zr + 200 + k);
                float4 a3 = *(const float4*)(zr + 300 + k);
                #pragma unroll
                for (int kk = 0; kk < 4; ++kk) {
                    const float* wr = pw1_w + (k + kk) * 384 + j0;
                    const float e0 = (&a0.x)[kk], e1 = (&a1.x)[kk], e2 = (&a2.x)[kk], e3 = (&a3.x)[kk];
                    #pragma unroll
                    for (int c = 0; c < 6; ++c) {
                        const float w = wr[c];
                        h[0][c] += e0 * w; h[1][c] += e1 * w;
                        h[2][c] += e2 * w; h[3][c] += e3 * w;
                    }
                }
            }
            #pragma unroll
            for (int r = 0; r < 4; ++r)
                #pragma unroll
                for (int c = 0; c < 6; ++c) {
                    float v = h[r][c] + pw1_b[j0 + c];
                    v = 0.5f * v * (1.f + erff(v * 0.70710678118654752f));
                    hb[(pxg * 4 + r) * 100 + sub * 6 + c] = v;
                }
        }
        __syncthreads();

        // ---- phase3: facc += h_chunk @ pw2[jc*96 : ..., :], 4px x 3f per thread ----
        {
            const float* hr = hb + pxg * 400;
            for (int k = 0; k < 96; k += 4) {
                float4 a0 = *(const float4*)(hr + k);
                float4 a1 = *(const float4*)(hr + 100 + k);
                float4 a2 = *(const float4*)(hr + 200 + k);
                float4 a3 = *(const float4*)(hr + 300 + k);
                #pragma unroll
                for (int kk = 0; kk < 4; ++kk) {
                    const float* wr = pw2_w + (jc * 96 + k + kk) * 48 + f0;
                    const float w0 = wr[0], w1 = wr[1], w2 = wr[2];
                    const float e0 = (&a0.x)[kk], e1 = (&a1.x)[kk], e2 = (&a2.x)[kk], e3 = (&a3.x)[kk];
                    facc[0][0] += e0 * w0; facc[0][1] += e0 * w1; facc[0][2] += e0 * w2;
                    facc[1][0] += e1 * w0; facc[1][1] += e1 * w1; facc[1][2] += e1 * w2;
                    facc[2][0] += e2 * w0; facc[2][1] += e2 * w1; facc[2][2] += e2 * w2;
                    facc[3][0] += e3 * w0; facc[3][1] += e3 * w1; facc[3][2] += e3 * w2;
                }
            }
        }
        __syncthreads();   // hb reused by next chunk; zb re-read
    }

    // ---- stage cat (x planar ch 0..47, t pixel-major ch 48..95) into zb ----
    for (int idx = tid; idx < 768; idx += THREADS) {
        int ch = idx >> 4, p0 = (idx & 15) << 2;
        float4 v = *(const float4*)(x + ((size_t)n * 48 + ch) * 4096 + hw0 + p0);
        zb[(p0 + 0) * 100 + ch] = v.x; zb[(p0 + 1) * 100 + ch] = v.y;
        zb[(p0 + 2) * 100 + ch] = v.z; zb[(p0 + 3) * 100 + ch] = v.w;
    }
    {
        const size_t tb = ((size_t)(n / 10) * 4096 + hw0);
        const int coff = (n % 10) * 48;
        for (int idx = tid; idx < 768; idx += THREADS) {
            int p = idx / 12, u0 = (idx % 12) * 4;
            float4 v = *(const float4*)(t_in + (tb + p) * 480 + coff + u0);
            *(float4*)(&zb[p * 100 + 48 + u0]) = v;
        }
    }
    __syncthreads();

    // ---- shortcut: facc += cat @ sc_w^T (sc_w is [48 out][96 in]) ----
    {
        const float* cr = zb + pxg * 400;
        for (int k = 0; k < 96; k += 4) {
            float4 a0 = *(const float4*)(cr + k);
            float4 a1 = *(const float4*)(cr + 100 + k);
            float4 a2 = *(const float4*)(cr + 200 + k);
            float4 a3 = *(const float4*)(cr + 300 + k);
            float4 w0 = *(const float4*)(sc_w + (f0 + 0) * 96 + k);
            float4 w1 = *(const float4*)(sc_w + (f0 + 1) * 96 + k);
            float4 w2 = *(const float4*)(sc_w + (f0 + 2) * 96 + k);
            #pragma unroll
            for (int kk = 0; kk < 4; ++kk) {
                const float e0 = (&a0.x)[kk], e1 = (&a1.x)[kk], e2 = (&a2.x)[kk], e3 = (&a3.x)[kk];
                const float q0 = (&w0.x)[kk], q1 = (&w1.x)[kk], q2 = (&w2.x)[kk];
                facc[0][0] += e0 * q0; facc[0][1] += e0 * q1; facc[0][2] += e0 * q2;
                facc[1][0] += e1 * q0; facc[1][1] += e1 * q1; facc[1][2] += e1 * q2;
                facc[2][0] += e2 * q0; facc[2][1] += e2 * q1; facc[2][2] += e2 * q2;
                facc[3][0] += e3 * q0; facc[3][1] += e3 * q1; facc[3][2] += e3 * q2;
            }
        }
    }
    __syncthreads();   // zb/hb done; reuse hb for output staging

    // ---- epilogue: stage [f][px] (stride 66), then coalesced float4 stores ----
    #pragma unroll
    for (int r = 0; r < 4; ++r)
        #pragma unroll
        for (int c = 0; c < 3; ++c)
            hb[(f0 + c) * 66 + pxg * 4 + r] = facc[r][c] + sc_b[f0 + c];
    __syncthreads();
    for (int idx = tid; idx < 768; idx += THREADS) {
        int f = idx / 16, p0 = (idx % 16) * 4;
        float4 v;
        v.x = hb[f * 66 + p0]; v.y = hb[f * 66 + p0 + 1];
        v.z = hb[f * 66 + p0 + 2]; v.w = hb[f * 66 + p0 + 3];
        *(float4*)(out + ((size_t)n * 48 + f) * 4096 + hw0 + p0) = v;
    }
}

extern "C" void kernel_launch(void* const* d_in, const int* in_sizes, int n_in,
                              void* d_out, int out_size, void* d_ws, size_t ws_size,
                              hipStream_t stream) {
    const float* x      = (const float*)d_in[0];
    const float* qkv_w  = (const float*)d_in[1];
    const float* qkv_b  = (const float*)d_in[2];
    const float* proj_w = (const float*)d_in[3];
    const float* proj_b = (const float*)d_in[4];
    const float* ff1_w  = (const float*)d_in[5];
    const float* ff1_b  = (const float*)d_in[6];
    const float* ff2_w  = (const float*)d_in[7];
    const float* ff2_b  = (const float*)d_in[8];
    const float* dw_w   = (const float*)d_in[9];
    const float* dw_b   = (const float*)d_in[10];
    const float* ln_g   = (const float*)d_in[11];
    const float* ln_b   = (const float*)d_in[12];
    const float* pw1_w  = (const float*)d_in[13];
    const float* pw1_b  = (const float*)d_in[14];
    const float* pw2_w  = (const float*)d_in[15];
    const float* pw2_b  = (const float*)d_in[16];
    const float* sc_w   = (const float*)d_in[17];
    const float* sc_b   = (const float*)d_in[18];
    float* out = (float*)d_out;

    // workspace: t_final (B*H*W,10,48) = 15,728,640 f ; z0 (80*4096,96) = 31,457,280 f
    float* t_out = (float*)d_ws;
    float* z0    = t_out + 15728640ull;

    // 32768 sequences, 6 per 1-wave block
    ka2_transformer<<<5462, 64, 0, stream>>>(x, qkv_w, qkv_b, proj_w, proj_b,
                                             ff1_w, ff1_b, ff2_w, ff2_b, t_out);
    kb_conv<<<5120, THREADS, 0, stream>>>(x, t_out, dw_w, dw_b, z0);
    kc_mlp<<<5120, THREADS, 0, stream>>>(x, t_out, z0, ln_g, ln_b,
                                         pw1_w, pw1_b, pw2_w, pw2_b, sc_w, sc_b, out);
}